// Round 1
// baseline (112.334 us; speedup 1.0000x reference)
//
#include <hip/hip_runtime.h>
#include <hip/hip_cooperative_groups.h>
#include <math.h>

namespace cg = cooperative_groups;

#define BB 16
#define SS 2048
#define NC 8
#define TILE 128
#define NT (SS/TILE)           // 16 tiles per batch row
#define NBLK (BB*NT)           // 256 blocks = 1 per CU, co-resident (cooperative OK)
#define LOG2E 1.4426950408889634f
#define LN2   0.6931471805599453f
#define T1V 100.0f
#define EPSV 1e-8f

__device__ __forceinline__ float fexp2(float x) {
#if __has_builtin(__builtin_amdgcn_exp2f)
    return __builtin_amdgcn_exp2f(x);
#else
    return exp2f(x);
#endif
}
__device__ __forceinline__ float flog2(float x) {
#if __has_builtin(__builtin_amdgcn_logf)
    return __builtin_amdgcn_logf(x);
#else
    return log2f(x);
#endif
}

// ONE cooperative dispatch replacing {memset, tilesum, main}:
//  - earlier-tile class sums g[c] recomputed per block (cheap: <=15 coalesced
//    rounds of 128 events, 1 exp2 each) instead of a separate kernel + E round-trip
//  - per-block partial -> ws, grid.sync(), block 0 reduces and writes out
__global__ __launch_bounds__(TILE) void hawkes_fused(
    const float* __restrict__ ts, const int* __restrict__ ms,
    const float* __restrict__ mu, const float* __restrict__ alphas,
    const float* __restrict__ beta, float* __restrict__ part,
    float* __restrict__ out)
{
    const int b    = blockIdx.x / NT;
    const int T    = blockIdx.x % NT;
    const int tid  = threadIdx.x;
    const int lane = tid & 63, wave = tid >> 6;

    __shared__ float sh_ab[NC*NC];   // alphas[r][c]*beta[c]
    __shared__ float sh_acol[NC];    // alphas[:,c].sum(0)
    __shared__ float sh_pc[NC];      // beta[c]*log2e
    __shared__ float sh_g[NC];       // earlier-events class sums (anchor-relative)
    __shared__ float sh_pu[TILE];    // p_j*t_j (or -1e30 invalid)
    __shared__ float sh_p[TILE];     // p_j
    __shared__ int   sh_m[TILE];
    __shared__ float shred[2*NC];

    const int   ig = b*SS + T*TILE + tid;
    const float ti = ts[ig];
    const int   mi = ms[ig];

    if (tid < NC*NC) {
        sh_ab[tid] = alphas[tid] * beta[tid & (NC-1)];
    }
    if (tid < NC) {
        float s = 0.0f;
        #pragma unroll
        for (int r = 0; r < NC; ++r) s += alphas[r*NC + tid];
        sh_acol[tid] = s;
        sh_pc[tid] = beta[tid] * LOG2E;
    }

    const float pi = beta[mi] * LOG2E;
    sh_p[tid]  = pi;
    sh_pu[tid] = (ti > 0.0f) ? pi * ti : -1e30f;
    sh_m[tid]  = mi;

    // anchor = last event time before this tile (ts sorted ascending)
    const float anchor = (T > 0) ? ts[b*SS + T*TILE - 1] : 0.0f;
    __syncthreads();

    // ---- earlier-events class sums, recomputed locally ----
    // g[c] = sum_{j < T*TILE, m_j=c, t_j>0} exp2(p_c*(t_j - anchor)); args <= 0.
    float gcl[NC];
    #pragma unroll
    for (int c = 0; c < NC; ++c) gcl[c] = 0.0f;
    for (int base = 0; base < T*TILE; base += TILE) {
        const int   jg = b*SS + base + tid;
        const float tj = ts[jg];
        const int   mj = ms[jg];
        const float e  = (tj > 0.0f) ? fexp2(sh_pc[mj] * (tj - anchor)) : 0.0f;
        #pragma unroll
        for (int c = 0; c < NC; ++c) gcl[c] += (mj == c) ? e : 0.0f;
    }
    #pragma unroll
    for (int c = 0; c < NC; ++c) {
        float v = gcl[c];
        for (int off = 32; off; off >>= 1) v += __shfl_xor(v, off, 64);
        if (lane == 0) shred[wave*NC + c] = v;
    }
    __syncthreads();
    if (tid < NC) sh_g[tid] = shred[tid] + shred[NC + tid];
    __syncthreads();

    const float* abrow = &sh_ab[mi*NC];
    float acc = 0.0f;

    // cross-tile contribution: 8 classes, decay from anchor to ti (arg <= 0)
    if (T > 0) {
        #pragma unroll
        for (int c = 0; c < NC; ++c) {
            const float dec = fexp2(sh_pc[c] * (anchor - ti));
            acc = fmaf(abrow[c] * sh_g[c], dec, acc);
        }
    }

    // intra-tile triangle: j < tid
    const int jfull = wave * 64;
    for (int j = 0; j < jfull; ++j) {
        const float arg = fmaf(-sh_p[j], ti, sh_pu[j]);
        acc = fmaf(abrow[sh_m[j]], fexp2(arg), acc);
    }
    #pragma unroll 4
    for (int jj = 0; jj < 64; ++jj) {
        const int j = jfull + jj;
        const float arg = fmaf(-sh_p[j], ti, sh_pu[j]);
        const float v = (jj < lane) ? abrow[sh_m[j]] * fexp2(arg) : 0.0f;
        acc += v;
    }

    // finalize this event: log-lambda and integral term
    float contrib = 0.0f;
    if (ti > 0.0f) {
        const float lam = acc + mu[mi];
        contrib = flog2(lam + EPSV) * LN2;
        const float tint = 1.0f - fexp2(-pi * (T1V - ti));
        contrib -= sh_acol[mi] * tint;
    }
    for (int off = 32; off; off >>= 1) contrib += __shfl_xor(contrib, off, 64);
    if (lane == 0) shred[wave] = contrib;
    __syncthreads();
    if (tid == 0) part[blockIdx.x] = shred[0] + shred[1];

    cg::this_grid().sync();

    // ---- final reduction in block 0 (replaces memset + 256 atomics) ----
    if (blockIdx.x == 0) {
        float v = part[tid] + part[tid + TILE];   // 256 partials
        for (int off = 32; off; off >>= 1) v += __shfl_xor(v, off, 64);
        if (lane == 0) shred[wave] = v;
        __syncthreads();
        if (tid == 0) {
            float msum = 0.0f;
            #pragma unroll
            for (int c = 0; c < NC; ++c) msum += mu[c];
            out[0] = shred[0] + shred[1] - msum * (T1V - 0.0f);
        }
    }
}

extern "C" void kernel_launch(void* const* d_in, const int* in_sizes, int n_in,
                              void* d_out, int out_size, void* d_ws, size_t ws_size,
                              hipStream_t stream) {
    const float* ts     = (const float*)d_in[0];
    const int*   ms     = (const int*)d_in[1];
    const float* mu     = (const float*)d_in[2];
    const float* alphas = (const float*)d_in[3];
    const float* beta   = (const float*)d_in[4];
    float* out  = (float*)d_out;
    float* part = (float*)d_ws;    // NBLK floats of workspace

    void* args[] = { (void*)&ts, (void*)&ms, (void*)&mu, (void*)&alphas,
                     (void*)&beta, (void*)&part, (void*)&out };
    hipLaunchCooperativeKernel((void*)hawkes_fused, dim3(NBLK), dim3(TILE),
                               args, 0, stream);
}

// Round 3
// 76.321 us; speedup vs baseline: 1.4719x; 1.4719x over previous
//
#include <hip/hip_runtime.h>
#include <math.h>

#define BB 16
#define SS 2048
#define NC 8
#define TILE 128
#define NT (SS/TILE)           // 16 tiles per batch row
#define NBLK (BB*NT)           // 256 blocks
#define LOG2E 1.4426950408889634f
#define LN2   0.6931471805599453f
#define T1V 100.0f
#define EPSV 1e-8f

__device__ __forceinline__ float fexp2(float x) {
#if __has_builtin(__builtin_amdgcn_exp2f)
    return __builtin_amdgcn_exp2f(x);
#else
    return exp2f(x);
#endif
}
__device__ __forceinline__ float flog2(float x) {
#if __has_builtin(__builtin_amdgcn_logf)
    return __builtin_amdgcn_logf(x);
#else
    return log2f(x);
#endif
}

// Single main kernel (plain launch): per-block everything, partial -> ws.
// Earlier-tile class sums g[c] recomputed locally (<=15 coalesced 128-wide
// rounds, 1 exp2 each) -- no separate kernel, no E round-trip, no grid sync.
__global__ __launch_bounds__(TILE) void hawkes_fused(
    const float* __restrict__ ts, const int* __restrict__ ms,
    const float* __restrict__ mu, const float* __restrict__ alphas,
    const float* __restrict__ beta, float* __restrict__ part)
{
    const int b    = blockIdx.x / NT;
    const int T    = blockIdx.x % NT;
    const int tid  = threadIdx.x;
    const int lane = tid & 63, wave = tid >> 6;

    __shared__ float sh_ab[NC*NC];   // alphas[r][c]*beta[c]
    __shared__ float sh_acol[NC];    // alphas[:,c].sum(0)
    __shared__ float sh_pc[NC];      // beta[c]*log2e
    __shared__ float sh_g[NC];       // earlier-events class sums (anchor-relative)
    __shared__ float sh_pu[TILE];    // p_j*t_j (or -1e30 invalid)
    __shared__ float sh_p[TILE];     // p_j
    __shared__ int   sh_m[TILE];
    __shared__ float shred[2*NC];

    const int   ig = b*SS + T*TILE + tid;
    const float ti = ts[ig];
    const int   mi = ms[ig];

    if (tid < NC*NC) {
        sh_ab[tid] = alphas[tid] * beta[tid & (NC-1)];
    }
    if (tid < NC) {
        float s = 0.0f;
        #pragma unroll
        for (int r = 0; r < NC; ++r) s += alphas[r*NC + tid];
        sh_acol[tid] = s;
        sh_pc[tid] = beta[tid] * LOG2E;
    }

    const float pi = beta[mi] * LOG2E;
    sh_p[tid]  = pi;
    sh_pu[tid] = (ti > 0.0f) ? pi * ti : -1e30f;
    sh_m[tid]  = mi;

    // anchor = last event time before this tile (ts sorted ascending)
    const float anchor = (T > 0) ? ts[b*SS + T*TILE - 1] : 0.0f;
    __syncthreads();

    // ---- earlier-events class sums, recomputed locally ----
    // g[c] = sum_{j < T*TILE, m_j=c, t_j>0} exp2(p_c*(t_j - anchor)); args <= 0.
    float gcl[NC];
    #pragma unroll
    for (int c = 0; c < NC; ++c) gcl[c] = 0.0f;
    for (int base = 0; base < T*TILE; base += TILE) {
        const int   jg = b*SS + base + tid;
        const float tj = ts[jg];
        const int   mj = ms[jg];
        const float e  = (tj > 0.0f) ? fexp2(sh_pc[mj] * (tj - anchor)) : 0.0f;
        #pragma unroll
        for (int c = 0; c < NC; ++c) gcl[c] += (mj == c) ? e : 0.0f;
    }
    #pragma unroll
    for (int c = 0; c < NC; ++c) {
        float v = gcl[c];
        for (int off = 32; off; off >>= 1) v += __shfl_xor(v, off, 64);
        if (lane == 0) shred[wave*NC + c] = v;
    }
    __syncthreads();
    if (tid < NC) sh_g[tid] = shred[tid] + shred[NC + tid];
    __syncthreads();

    const float* abrow = &sh_ab[mi*NC];
    float acc = 0.0f;

    // cross-tile contribution: 8 classes, decay from anchor to ti (arg <= 0)
    if (T > 0) {
        #pragma unroll
        for (int c = 0; c < NC; ++c) {
            const float dec = fexp2(sh_pc[c] * (anchor - ti));
            acc = fmaf(abrow[c] * sh_g[c], dec, acc);
        }
    }

    // intra-tile triangle: j < tid
    const int jfull = wave * 64;
    for (int j = 0; j < jfull; ++j) {
        const float arg = fmaf(-sh_p[j], ti, sh_pu[j]);
        acc = fmaf(abrow[sh_m[j]], fexp2(arg), acc);
    }
    #pragma unroll 4
    for (int jj = 0; jj < 64; ++jj) {
        const int j = jfull + jj;
        const float arg = fmaf(-sh_p[j], ti, sh_pu[j]);
        const float v = (jj < lane) ? abrow[sh_m[j]] * fexp2(arg) : 0.0f;
        acc += v;
    }

    // finalize this event: log-lambda and integral term
    float contrib = 0.0f;
    if (ti > 0.0f) {
        const float lam = acc + mu[mi];
        contrib = flog2(lam + EPSV) * LN2;
        const float tint = 1.0f - fexp2(-pi * (T1V - ti));
        contrib -= sh_acol[mi] * tint;
    }
    for (int off = 32; off; off >>= 1) contrib += __shfl_xor(contrib, off, 64);
    if (lane == 0) shred[wave] = contrib;
    __syncthreads();
    if (tid == 0) part[blockIdx.x] = shred[0] + shred[1];
}

// Tiny reducer: one block sums the 256 partials and writes out directly.
// No atomics -> no output zero-init node required.
__global__ __launch_bounds__(256) void hawkes_reduce(
    const float* __restrict__ part, const float* __restrict__ mu,
    float* __restrict__ out)
{
    const int tid = threadIdx.x;
    const int lane = tid & 63, wave = tid >> 6;
    __shared__ float shred[4];

    float v = (tid < NBLK) ? part[tid] : 0.0f;
    for (int off = 32; off; off >>= 1) v += __shfl_xor(v, off, 64);
    if (lane == 0) shred[wave] = v;
    __syncthreads();
    if (tid == 0) {
        float msum = 0.0f;
        #pragma unroll
        for (int c = 0; c < NC; ++c) msum += mu[c];
        out[0] = shred[0] + shred[1] + shred[2] + shred[3]
               - msum * (T1V - 0.0f);
    }
}

extern "C" void kernel_launch(void* const* d_in, const int* in_sizes, int n_in,
                              void* d_out, int out_size, void* d_ws, size_t ws_size,
                              hipStream_t stream) {
    const float* ts     = (const float*)d_in[0];
    const int*   ms     = (const int*)d_in[1];
    const float* mu     = (const float*)d_in[2];
    const float* alphas = (const float*)d_in[3];
    const float* beta   = (const float*)d_in[4];
    float* out  = (float*)d_out;
    float* part = (float*)d_ws;    // NBLK floats of workspace

    hawkes_fused<<<NBLK, TILE, 0, stream>>>(ts, ms, mu, alphas, beta, part);
    hawkes_reduce<<<1, 256, 0, stream>>>(part, mu, out);
}